// Round 13
// baseline (80.139 us; speedup 1.0000x reference)
//
#include <hip/hip_runtime.h>
#include <hip/hip_bf16.h>

// ============ INSTRUMENTATION BUILD ============
// R10-best source with the two hot kernels wrapped in x3 idempotent repeat
// loops so they exceed the ~40us harness memsets and surface in rocprof's
// top-5 WITH counters. Perf number this round is sacrificial; divide hot
// kernel durations by 3.
#define REPS 3

#define B_ 16
#define C_ 64
#define N_ 16384          // 128*128
#define KCH 32            // gram chunks per batch -> 512 blocks
#define CPB 512           // columns per gram block (N_/KCH)
#define SROW 72           // Xt row stride in bf16 (pad 64 -> 72)

typedef __attribute__((ext_vector_type(8))) short bf16x8;
typedef __attribute__((ext_vector_type(4))) float f32x4;
typedef __attribute__((ext_vector_type(4))) short s16x4;

// fp32 -> bf16 RNE via HW cvt (compiler fuses pairs into v_cvt_pk_bf16_f32)
__device__ __forceinline__ short f2bf(float f) {
    return (short)__bfloat16_as_ushort(__float2bfloat16(f));
}

__device__ __forceinline__ bf16x8 cvt8(float4 lo, float4 hi) {
    bf16x8 r;
    r[0] = f2bf(lo.x); r[1] = f2bf(lo.y); r[2] = f2bf(lo.z); r[3] = f2bf(lo.w);
    r[4] = f2bf(hi.x); r[5] = f2bf(hi.y); r[6] = f2bf(hi.z); r[7] = f2bf(hi.w);
    return r;
}

// -------- pass 1: per-(batch, k-chunk) partial gram via bf16 MFMA --------
__global__ __launch_bounds__(256)
void gram_kernel(const float* __restrict__ x, float* __restrict__ gpart) {
    __shared__ float red[2][4096];
    const int t = threadIdx.x, l = t & 63, w = t >> 6;
    const int b = blockIdx.y, ch = blockIdx.x;
    const float* xb = x + (size_t)b * (C_ * (size_t)N_);
    const int row = l & 15, kg = l >> 4;
    const int kbase = ch * CPB + w * (CPB / 4);

    #pragma unroll 1
    for (int rep = 0; rep < REPS; ++rep) {
        f32x4 acc[4][4] = {};
        float4 raw[2][4][2];

        #pragma unroll
        for (int g = 0; g < 4; ++g) {
            const float* p = xb + (size_t)(16 * g + row) * N_ + kbase + kg * 8;
            raw[0][g][0] = *(const float4*)p;
            raw[0][g][1] = *(const float4*)(p + 4);
        }

        #pragma unroll
        for (int ks = 0; ks < 4; ++ks) {
            const int cb = ks & 1, nb = cb ^ 1;
            if (ks < 3) {
                #pragma unroll
                for (int g = 0; g < 4; ++g) {
                    const float* p = xb + (size_t)(16 * g + row) * N_ +
                                     kbase + (ks + 1) * 32 + kg * 8;
                    raw[nb][g][0] = *(const float4*)p;
                    raw[nb][g][1] = *(const float4*)(p + 4);
                }
            }
            bf16x8 fr[4];
            #pragma unroll
            for (int g = 0; g < 4; ++g) fr[g] = cvt8(raw[cb][g][0], raw[cb][g][1]);
            #pragma unroll
            for (int gc = 0; gc < 4; ++gc)
                #pragma unroll
                for (int gd = 0; gd < 4; ++gd)
                    acc[gc][gd] = __builtin_amdgcn_mfma_f32_16x16x32_bf16(
                        fr[gc], fr[gd], acc[gc][gd], 0, 0, 0);
        }

        if (w < 2) {
            #pragma unroll
            for (int gc = 0; gc < 4; ++gc)
                #pragma unroll
                for (int gd = 0; gd < 4; ++gd)
                    *(f32x4*)&red[w][(gc * 4 + gd) * 256 + l * 4] = acc[gc][gd];
        }
        __syncthreads();
        if (w >= 2) {
            #pragma unroll
            for (int gc = 0; gc < 4; ++gc)
                #pragma unroll
                for (int gd = 0; gd < 4; ++gd) {
                    float* p = &red[w - 2][(gc * 4 + gd) * 256 + l * 4];
                    f32x4 v = *(f32x4*)p;
                    *(f32x4*)p = v + acc[gc][gd];
                }
        }
        __syncthreads();

        f32x4* dst = (f32x4*)(gpart + ((size_t)b * KCH + ch) * 4096);
        const f32x4* r0 = (const f32x4*)red[0];
        const f32x4* r1 = (const f32x4*)red[1];
        #pragma unroll
        for (int j = 0; j < 4; ++j)
            dst[j * 256 + t] = r0[j * 256 + t] + r1[j * 256 + t];

        __syncthreads();   // WAR: dst reads of red done before next rep rewrites
    }
}

// -------- pass 2 (merged reduce+m, FULL load ILP) — R10 exact, 1x --------
__global__ __launch_bounds__(256)
void rm_kernel(const float* __restrict__ W, const float* __restrict__ gpart,
               unsigned short* __restrict__ Mbf) {
    __shared__ float Gs[C_][17];
    __shared__ float Ws[C_][65];
    const int gd = blockIdx.x, b = blockIdx.y, t = threadIdx.x;

    for (int i = t; i < C_ * C_; i += 256) Ws[i >> 6][i & 63] = W[i];

    const int f = t;
    #pragma unroll
    for (int gc = 0; gc < 4; ++gc) {
        const float* p = gpart + (size_t)b * KCH * 4096 + (gc * 4 + gd) * 256 + f;
        float v[KCH];
        #pragma unroll
        for (int ch = 0; ch < KCH; ++ch)
            v[ch] = p[(size_t)ch * 4096];
        float s = 0.f;
        #pragma unroll
        for (int ch = 0; ch < KCH; ch += 4)
            s += ((v[ch] + v[ch + 1]) + (v[ch + 2] + v[ch + 3]));
        const int c = gc * 16 + (f >> 6) * 4 + (f & 3);
        const int dloc = (f >> 2) & 15;
        Gs[c][dloc] = s;
    }
    __syncthreads();

    const int o = t & 63, g2 = t >> 6;
    const float invN = 1.0f / (float)N_;
    #pragma unroll
    for (int j = 0; j < 4; ++j) {
        const int dloc = g2 * 4 + j;
        float s = 0.f;
        #pragma unroll
        for (int c = 0; c < C_; ++c) s = fmaf(Ws[o][c], Gs[c][dloc], s);
        Mbf[((size_t)b * C_ + o) * C_ + gd * 16 + dloc] = (unsigned short)f2bf(s * invN);
    }
}

// -------- pass 3: out_b = M_b @ X_b, operand-swapped, nt stores (R10) --------
__global__ __launch_bounds__(256, 4)
void out_kernel(const float* __restrict__ x, const unsigned short* __restrict__ Mbf,
                float* __restrict__ out) {
    __shared__ unsigned short Xt[256][SROW];
    const int t = threadIdx.x, l = t & 63, w = t >> 6;
    const int b = blockIdx.y, n0 = blockIdx.x * 256;
    const float* xb = x + (size_t)b * (C_ * (size_t)N_);
    const int row = l & 15, kg = l >> 4;

    bf16x8 mfrag[2][4];
    #pragma unroll
    for (int ks = 0; ks < 2; ++ks)
        #pragma unroll
        for (int g = 0; g < 4; ++g)
            mfrag[ks][g] = *(const bf16x8*)((const short*)Mbf +
                ((size_t)b * C_ + 16 * g + row) * C_ + ks * 32 + kg * 8);

    const int d0 = (t & 15) * 4, nb2 = (t >> 4) * 16;

    #pragma unroll 1
    for (int rep = 0; rep < REPS; ++rep) {
        if (rep) __syncthreads();   // WAR: prior compute's LDS reads done

        #pragma unroll
        for (int p = 0; p < 2; ++p) {
            const int n8 = nb2 + p * 8;
            float a[4][8];
            #pragma unroll
            for (int r = 0; r < 4; ++r) {
                const float* src = xb + (size_t)(d0 + r) * N_ + n0 + n8;
                float4 q0 = *(const float4*)src;
                float4 q1 = *(const float4*)(src + 4);
                a[r][0] = q0.x; a[r][1] = q0.y; a[r][2] = q0.z; a[r][3] = q0.w;
                a[r][4] = q1.x; a[r][5] = q1.y; a[r][6] = q1.z; a[r][7] = q1.w;
            }
            #pragma unroll
            for (int j = 0; j < 8; ++j) {
                s16x4 pk;
                pk[0] = f2bf(a[0][j]); pk[1] = f2bf(a[1][j]);
                pk[2] = f2bf(a[2][j]); pk[3] = f2bf(a[3][j]);
                *(s16x4*)&Xt[n8 + j][d0] = pk;
            }
        }
        __syncthreads();

        float* ob = out + (size_t)b * (C_ * (size_t)N_);
        #pragma unroll
        for (int nt = 0; nt < 4; ++nt) {
            const int ntile = w * 4 + nt;
            bf16x8 xfrag0 = *(const bf16x8*)&Xt[ntile * 16 + row][kg * 8];
            bf16x8 xfrag1 = *(const bf16x8*)&Xt[ntile * 16 + row][32 + kg * 8];
            #pragma unroll
            for (int g = 0; g < 4; ++g) {
                f32x4 acc = {};
                acc = __builtin_amdgcn_mfma_f32_16x16x32_bf16(xfrag0, mfrag[0][g], acc, 0, 0, 0);
                acc = __builtin_amdgcn_mfma_f32_16x16x32_bf16(xfrag1, mfrag[1][g], acc, 0, 0, 0);
                __builtin_nontemporal_store(acc,
                    (f32x4*)&ob[(size_t)(16 * g + row) * N_ + n0 + ntile * 16 + 4 * kg]);
            }
        }
    }
}

extern "C" void kernel_launch(void* const* d_in, const int* in_sizes, int n_in,
                              void* d_out, int out_size, void* d_ws, size_t ws_size,
                              hipStream_t stream) {
    const float* x = (const float*)d_in[0];   // [16,64,128,128] fp32
    const float* w = (const float*)d_in[1];   // [64,64] fp32
    float* out = (float*)d_out;               // [16,64,128,128] fp32

    float* gpart = (float*)d_ws;                                      // 8 MiB
    unsigned short* Mbf = (unsigned short*)(gpart + (size_t)B_ * KCH * 4096);  // 128 KiB

    gram_kernel<<<dim3(KCH, B_), 256, 0, stream>>>(x, gpart);
    rm_kernel<<<dim3(4, B_), 256, 0, stream>>>(w, gpart, Mbf);
    out_kernel<<<dim3(N_ / 256, B_), 256, 0, stream>>>(x, Mbf, out);
}

// Round 14
// 53.139 us; speedup vs baseline: 1.5081x; 1.5081x over previous
//
#include <hip/hip_runtime.h>
#include <hip/hip_bf16.h>

#define B_ 16
#define C_ 64
#define N_ 16384          // 128*128
#define KCH 32            // gram chunks per batch -> 512 blocks
#define CPB 512           // columns per gram block (N_/KCH)
#define SROW 72           // Xt row stride in bf16 (pad 64 -> 72)

typedef __attribute__((ext_vector_type(8))) short bf16x8;
typedef __attribute__((ext_vector_type(4))) float f32x4;
typedef __attribute__((ext_vector_type(4))) short s16x4;

// fp32 -> bf16 RNE via HW cvt (compiler fuses pairs into v_cvt_pk_bf16_f32)
__device__ __forceinline__ short f2bf(float f) {
    return (short)__bfloat16_as_ushort(__float2bfloat16(f));
}

__device__ __forceinline__ bf16x8 cvt8(float4 lo, float4 hi) {
    bf16x8 r;
    r[0] = f2bf(lo.x); r[1] = f2bf(lo.y); r[2] = f2bf(lo.z); r[3] = f2bf(lo.w);
    r[4] = f2bf(hi.x); r[5] = f2bf(hi.y); r[6] = f2bf(hi.z); r[7] = f2bf(hi.w);
    return r;
}

// -------- pass 1: per-(batch, k-chunk) partial gram via bf16 MFMA --------
// R10 body exact. R13 instrumentation: ~10-12us cold, near the 10.2us
// 64MiB read floor -- leave alone.
__global__ __launch_bounds__(256)
void gram_kernel(const float* __restrict__ x, float* __restrict__ gpart) {
    __shared__ float red[2][4096];   // 32 KiB two-phase reduce buffer
    const int t = threadIdx.x, l = t & 63, w = t >> 6;
    const int b = blockIdx.y, ch = blockIdx.x;
    const float* xb = x + (size_t)b * (C_ * (size_t)N_);
    const int row = l & 15, kg = l >> 4;
    const int kbase = ch * CPB + w * (CPB / 4);

    f32x4 acc[4][4] = {};
    float4 raw[2][4][2];

    // preload k-step 0
    #pragma unroll
    for (int g = 0; g < 4; ++g) {
        const float* p = xb + (size_t)(16 * g + row) * N_ + kbase + kg * 8;
        raw[0][g][0] = *(const float4*)p;
        raw[0][g][1] = *(const float4*)(p + 4);
    }

    #pragma unroll
    for (int ks = 0; ks < 4; ++ks) {
        const int cb = ks & 1, nb = cb ^ 1;
        if (ks < 3) {   // issue next k-step's 8 loads before touching current
            #pragma unroll
            for (int g = 0; g < 4; ++g) {
                const float* p = xb + (size_t)(16 * g + row) * N_ +
                                 kbase + (ks + 1) * 32 + kg * 8;
                raw[nb][g][0] = *(const float4*)p;
                raw[nb][g][1] = *(const float4*)(p + 4);
            }
        }
        bf16x8 fr[4];
        #pragma unroll
        for (int g = 0; g < 4; ++g) fr[g] = cvt8(raw[cb][g][0], raw[cb][g][1]);
        #pragma unroll
        for (int gc = 0; gc < 4; ++gc)
            #pragma unroll
            for (int gd = 0; gd < 4; ++gd)
                acc[gc][gd] = __builtin_amdgcn_mfma_f32_16x16x32_bf16(
                    fr[gc], fr[gd], acc[gc][gd], 0, 0, 0);
    }

    // two-phase block reduce: waves 0,1 write; waves 2,3 add; all sum halves.
    if (w < 2) {
        #pragma unroll
        for (int gc = 0; gc < 4; ++gc)
            #pragma unroll
            for (int gd = 0; gd < 4; ++gd)
                *(f32x4*)&red[w][(gc * 4 + gd) * 256 + l * 4] = acc[gc][gd];
    }
    __syncthreads();
    if (w >= 2) {
        #pragma unroll
        for (int gc = 0; gc < 4; ++gc)
            #pragma unroll
            for (int gd = 0; gd < 4; ++gd) {
                float* p = &red[w - 2][(gc * 4 + gd) * 256 + l * 4];
                f32x4 v = *(f32x4*)p;
                *(f32x4*)p = v + acc[gc][gd];
            }
    }
    __syncthreads();

    f32x4* dst = (f32x4*)(gpart + ((size_t)b * KCH + ch) * 4096);
    const f32x4* r0 = (const f32x4*)red[0];
    const f32x4* r1 = (const f32x4*)red[1];
    #pragma unroll
    for (int j = 0; j < 4; ++j)
        dst[j * 256 + t] = r0[j * 256 + t] + r1[j * 256 + t];
}

// -------- pass 2 (merged reduce+m, FULL load ILP) — R10 exact --------
__global__ __launch_bounds__(256)
void rm_kernel(const float* __restrict__ W, const float* __restrict__ gpart,
               unsigned short* __restrict__ Mbf) {
    __shared__ float Gs[C_][17];   // [c][dloc]
    __shared__ float Ws[C_][65];   // [o][c]
    const int gd = blockIdx.x, b = blockIdx.y, t = threadIdx.x;

    for (int i = t; i < C_ * C_; i += 256) Ws[i >> 6][i & 63] = W[i];

    const int f = t;  // flat in-tile index = lane*4 + reg
    #pragma unroll
    for (int gc = 0; gc < 4; ++gc) {
        const float* p = gpart + (size_t)b * KCH * 4096 + (gc * 4 + gd) * 256 + f;
        float v[KCH];
        #pragma unroll
        for (int ch = 0; ch < KCH; ++ch)           // 32 loads, all in flight
            v[ch] = p[(size_t)ch * 4096];
        float s = 0.f;
        #pragma unroll
        for (int ch = 0; ch < KCH; ch += 4)        // 4-chain tree sum
            s += ((v[ch] + v[ch + 1]) + (v[ch + 2] + v[ch + 3]));
        const int c = gc * 16 + (f >> 6) * 4 + (f & 3);
        const int dloc = (f >> 2) & 15;
        Gs[c][dloc] = s;
    }
    __syncthreads();

    const int o = t & 63, g2 = t >> 6;
    const float invN = 1.0f / (float)N_;
    #pragma unroll
    for (int j = 0; j < 4; ++j) {
        const int dloc = g2 * 4 + j;
        float s = 0.f;
        #pragma unroll
        for (int c = 0; c < C_; ++c) s = fmaf(Ws[o][c], Gs[c][dloc], s);
        Mbf[((size_t)b * C_ + o) * C_ + gd * 16 + dloc] = (unsigned short)f2bf(s * invN);
    }
}

// -------- pass 3: out_b = M_b @ X_b, operand-swapped, LINE-PAIRED stores --------
// R13 counters: WRITE 81MB/rep vs 67MB ideal (partial-line waste). Fix: hoist
// all 16 acc tiles, then store g-major/nt-inner so the two 64B halves of each
// 128B output line (ntile, ntile+1) are back-to-back store instructions ->
// L2 merges before (nt-policy) eviction.
__global__ __launch_bounds__(256, 4)
void out_kernel(const float* __restrict__ x, const unsigned short* __restrict__ Mbf,
                float* __restrict__ out) {
    __shared__ unsigned short Xt[256][SROW];   // 36 KiB
    const int t = threadIdx.x, l = t & 63, w = t >> 6;
    const int b = blockIdx.y, n0 = blockIdx.x * 256;
    const float* xb = x + (size_t)b * (C_ * (size_t)N_);
    const int row = l & 15, kg = l >> 4;

    // M fragments: lane l -> M[16g+row][ks*32 + kg*8 + j]  (used as B operand)
    bf16x8 mfrag[2][4];
    #pragma unroll
    for (int ks = 0; ks < 2; ++ks)
        #pragma unroll
        for (int g = 0; g < 4; ++g)
            mfrag[ks][g] = *(const bf16x8*)((const short*)Mbf +
                ((size_t)b * C_ + 16 * g + row) * C_ + ks * 32 + kg * 8);

    // stage+transpose: thread t -> d-quad d0 = (t&15)*4, n-block = (t>>4)*16,
    // two 8-n halves to bound register pressure; ds_write_b64 packs 4 d's.
    const int d0 = (t & 15) * 4, nb2 = (t >> 4) * 16;
    #pragma unroll
    for (int p = 0; p < 2; ++p) {
        const int n8 = nb2 + p * 8;
        float a[4][8];
        #pragma unroll
        for (int r = 0; r < 4; ++r) {
            const float* src = xb + (size_t)(d0 + r) * N_ + n0 + n8;
            float4 q0 = *(const float4*)src;
            float4 q1 = *(const float4*)(src + 4);
            a[r][0] = q0.x; a[r][1] = q0.y; a[r][2] = q0.z; a[r][3] = q0.w;
            a[r][4] = q1.x; a[r][5] = q1.y; a[r][6] = q1.z; a[r][7] = q1.w;
        }
        #pragma unroll
        for (int j = 0; j < 8; ++j) {
            s16x4 pk;
            pk[0] = f2bf(a[0][j]); pk[1] = f2bf(a[1][j]);
            pk[2] = f2bf(a[2][j]); pk[3] = f2bf(a[3][j]);
            *(s16x4*)&Xt[n8 + j][d0] = pk;
        }
    }
    __syncthreads();

    // compute ALL 16 acc tiles first (acc[nt][g], compile-time indexed)
    f32x4 acc[4][4];
    #pragma unroll
    for (int nt = 0; nt < 4; ++nt) {
        const int ntile = w * 4 + nt;
        bf16x8 xfrag0 = *(const bf16x8*)&Xt[ntile * 16 + row][kg * 8];
        bf16x8 xfrag1 = *(const bf16x8*)&Xt[ntile * 16 + row][32 + kg * 8];
        #pragma unroll
        for (int g = 0; g < 4; ++g) {
            f32x4 a = {};
            a = __builtin_amdgcn_mfma_f32_16x16x32_bf16(xfrag0, mfrag[0][g], a, 0, 0, 0);
            a = __builtin_amdgcn_mfma_f32_16x16x32_bf16(xfrag1, mfrag[1][g], a, 0, 0, 0);
            acc[nt][g] = a;
        }
    }

    // store g-major, nt-inner: per output row, the four 64B segments
    // (nt=0..3) are issued back-to-back -> full 128B lines in L2.
    float* ob = out + (size_t)b * (C_ * (size_t)N_);
    #pragma unroll
    for (int g = 0; g < 4; ++g) {
        float* rowp = &ob[(size_t)(16 * g + row) * N_ + n0 + w * 64 + 4 * kg];
        #pragma unroll
        for (int nt = 0; nt < 4; ++nt)
            __builtin_nontemporal_store(acc[nt][g], (f32x4*)(rowp + nt * 16));
    }
}

extern "C" void kernel_launch(void* const* d_in, const int* in_sizes, int n_in,
                              void* d_out, int out_size, void* d_ws, size_t ws_size,
                              hipStream_t stream) {
    const float* x = (const float*)d_in[0];   // [16,64,128,128] fp32
    const float* w = (const float*)d_in[1];   // [64,64] fp32
    float* out = (float*)d_out;               // [16,64,128,128] fp32

    float* gpart = (float*)d_ws;                                      // 8 MiB
    unsigned short* Mbf = (unsigned short*)(gpart + (size_t)B_ * KCH * 4096);  // 128 KiB

    gram_kernel<<<dim3(KCH, B_), 256, 0, stream>>>(x, gpart);
    rm_kernel<<<dim3(4, B_), 256, 0, stream>>>(w, gpart, Mbf);
    out_kernel<<<dim3(N_ / 256, B_), 256, 0, stream>>>(x, Mbf, out);
}

// Round 15
// 51.497 us; speedup vs baseline: 1.5562x; 1.0319x over previous
//
#include <hip/hip_runtime.h>
#include <hip/hip_bf16.h>

#define B_ 16
#define C_ 64
#define N_ 16384          // 128*128
#define KCH 32            // gram chunks per batch -> 512 blocks
#define CPB 512           // columns per gram block (N_/KCH)
#define SROW 72           // Xt row stride in bf16 (pad 64 -> 72)

typedef __attribute__((ext_vector_type(8))) short bf16x8;
typedef __attribute__((ext_vector_type(4))) float f32x4;
typedef __attribute__((ext_vector_type(4))) short s16x4;

// fp32 -> bf16 RNE via HW cvt (compiler fuses pairs into v_cvt_pk_bf16_f32)
__device__ __forceinline__ short f2bf(float f) {
    return (short)__bfloat16_as_ushort(__float2bfloat16(f));
}

__device__ __forceinline__ float bf2f(unsigned short u) {
    unsigned int x = ((unsigned int)u) << 16;
    return __uint_as_float(x);
}

__device__ __forceinline__ bf16x8 cvt8(float4 lo, float4 hi) {
    bf16x8 r;
    r[0] = f2bf(lo.x); r[1] = f2bf(lo.y); r[2] = f2bf(lo.z); r[3] = f2bf(lo.w);
    r[4] = f2bf(hi.x); r[5] = f2bf(hi.y); r[6] = f2bf(hi.z); r[7] = f2bf(hi.w);
    return r;
}

// -------- pass 1: per-(batch, k-chunk) partial gram via bf16 MFMA --------
// R10 body, single change: partials stored as bf16 (halves gpart traffic:
// 8MiB->4MiB roundtrip). Partials are +-22 off-diag / ~512 diag; bf16 RNE
// adds ~0.2% on G after the 32-chunk sum -- well within the 3x absmax margin.
__global__ __launch_bounds__(256)
void gram_kernel(const float* __restrict__ x, unsigned short* __restrict__ gpart) {
    __shared__ float red[2][4096];   // 32 KiB two-phase reduce buffer
    const int t = threadIdx.x, l = t & 63, w = t >> 6;
    const int b = blockIdx.y, ch = blockIdx.x;
    const float* xb = x + (size_t)b * (C_ * (size_t)N_);
    const int row = l & 15, kg = l >> 4;
    const int kbase = ch * CPB + w * (CPB / 4);

    f32x4 acc[4][4] = {};
    float4 raw[2][4][2];

    // preload k-step 0
    #pragma unroll
    for (int g = 0; g < 4; ++g) {
        const float* p = xb + (size_t)(16 * g + row) * N_ + kbase + kg * 8;
        raw[0][g][0] = *(const float4*)p;
        raw[0][g][1] = *(const float4*)(p + 4);
    }

    #pragma unroll
    for (int ks = 0; ks < 4; ++ks) {
        const int cb = ks & 1, nb = cb ^ 1;
        if (ks < 3) {   // issue next k-step's 8 loads before touching current
            #pragma unroll
            for (int g = 0; g < 4; ++g) {
                const float* p = xb + (size_t)(16 * g + row) * N_ +
                                 kbase + (ks + 1) * 32 + kg * 8;
                raw[nb][g][0] = *(const float4*)p;
                raw[nb][g][1] = *(const float4*)(p + 4);
            }
        }
        bf16x8 fr[4];
        #pragma unroll
        for (int g = 0; g < 4; ++g) fr[g] = cvt8(raw[cb][g][0], raw[cb][g][1]);
        #pragma unroll
        for (int gc = 0; gc < 4; ++gc)
            #pragma unroll
            for (int gd = 0; gd < 4; ++gd)
                acc[gc][gd] = __builtin_amdgcn_mfma_f32_16x16x32_bf16(
                    fr[gc], fr[gd], acc[gc][gd], 0, 0, 0);
    }

    // two-phase block reduce: waves 0,1 write; waves 2,3 add; all sum halves.
    if (w < 2) {
        #pragma unroll
        for (int gc = 0; gc < 4; ++gc)
            #pragma unroll
            for (int gd = 0; gd < 4; ++gd)
                *(f32x4*)&red[w][(gc * 4 + gd) * 256 + l * 4] = acc[gc][gd];
    }
    __syncthreads();
    if (w >= 2) {
        #pragma unroll
        for (int gc = 0; gc < 4; ++gc)
            #pragma unroll
            for (int gd = 0; gd < 4; ++gd) {
                float* p = &red[w - 2][(gc * 4 + gd) * 256 + l * 4];
                f32x4 v = *(f32x4*)p;
                *(f32x4*)p = v + acc[gc][gd];
            }
    }
    __syncthreads();

    // pack 8 fp32 -> bf16x8 (16B store); each thread covers elems [8t, 8t+8)
    unsigned short* dst = gpart + ((size_t)b * KCH + ch) * 4096;
    const float* r0 = red[0];
    const float* r1 = red[1];
    #pragma unroll
    for (int j = 0; j < 2; ++j) {
        const int e = j * 2048 + t * 8;
        bf16x8 pk;
        #pragma unroll
        for (int q = 0; q < 8; ++q) pk[q] = f2bf(r0[e + q] + r1[e + q]);
        *(bf16x8*)(dst + e) = pk;
    }
}

// -------- pass 2 (merged reduce+m, FULL load ILP) — bf16 partial reads --------
__global__ __launch_bounds__(256)
void rm_kernel(const float* __restrict__ W, const unsigned short* __restrict__ gpart,
               unsigned short* __restrict__ Mbf) {
    __shared__ float Gs[C_][17];   // [c][dloc]
    __shared__ float Ws[C_][65];   // [o][c]
    const int gd = blockIdx.x, b = blockIdx.y, t = threadIdx.x;

    for (int i = t; i < C_ * C_; i += 256) Ws[i >> 6][i & 63] = W[i];

    const int f = t;  // flat in-tile index = lane*4 + reg
    #pragma unroll
    for (int gc = 0; gc < 4; ++gc) {
        const unsigned short* p = gpart + (size_t)b * KCH * 4096 + (gc * 4 + gd) * 256 + f;
        unsigned short v[KCH];
        #pragma unroll
        for (int ch = 0; ch < KCH; ++ch)           // 32 loads, all in flight
            v[ch] = p[(size_t)ch * 4096];
        float s = 0.f;
        #pragma unroll
        for (int ch = 0; ch < KCH; ch += 4)        // 4-chain tree sum
            s += ((bf2f(v[ch]) + bf2f(v[ch + 1])) + (bf2f(v[ch + 2]) + bf2f(v[ch + 3])));
        const int c = gc * 16 + (f >> 6) * 4 + (f & 3);
        const int dloc = (f >> 2) & 15;
        Gs[c][dloc] = s;
    }
    __syncthreads();

    const int o = t & 63, g2 = t >> 6;
    const float invN = 1.0f / (float)N_;
    #pragma unroll
    for (int j = 0; j < 4; ++j) {
        const int dloc = g2 * 4 + j;
        float s = 0.f;
        #pragma unroll
        for (int c = 0; c < C_; ++c) s = fmaf(Ws[o][c], Gs[c][dloc], s);
        Mbf[((size_t)b * C_ + o) * C_ + gd * 16 + dloc] = (unsigned short)f2bf(s * invN);
    }
}

// -------- pass 3: out_b = M_b @ X_b, operand-swapped, nt stores (R10 exact) --------
__global__ __launch_bounds__(256, 4)
void out_kernel(const float* __restrict__ x, const unsigned short* __restrict__ Mbf,
                float* __restrict__ out) {
    __shared__ unsigned short Xt[256][SROW];   // 36 KiB
    const int t = threadIdx.x, l = t & 63, w = t >> 6;
    const int b = blockIdx.y, n0 = blockIdx.x * 256;
    const float* xb = x + (size_t)b * (C_ * (size_t)N_);
    const int row = l & 15, kg = l >> 4;

    // M fragments: lane l -> M[16g+row][ks*32 + kg*8 + j]  (used as B operand)
    bf16x8 mfrag[2][4];
    #pragma unroll
    for (int ks = 0; ks < 2; ++ks)
        #pragma unroll
        for (int g = 0; g < 4; ++g)
            mfrag[ks][g] = *(const bf16x8*)((const short*)Mbf +
                ((size_t)b * C_ + 16 * g + row) * C_ + ks * 32 + kg * 8);

    // stage+transpose: thread t -> d-quad d0 = (t&15)*4, n-block = (t>>4)*16,
    // two 8-n halves to bound register pressure; ds_write_b64 packs 4 d's.
    const int d0 = (t & 15) * 4, nb2 = (t >> 4) * 16;
    #pragma unroll
    for (int p = 0; p < 2; ++p) {
        const int n8 = nb2 + p * 8;
        float a[4][8];
        #pragma unroll
        for (int r = 0; r < 4; ++r) {
            const float* src = xb + (size_t)(d0 + r) * N_ + n0 + n8;
            float4 q0 = *(const float4*)src;
            float4 q1 = *(const float4*)(src + 4);
            a[r][0] = q0.x; a[r][1] = q0.y; a[r][2] = q0.z; a[r][3] = q0.w;
            a[r][4] = q1.x; a[r][5] = q1.y; a[r][6] = q1.z; a[r][7] = q1.w;
        }
        #pragma unroll
        for (int j = 0; j < 8; ++j) {
            s16x4 pk;
            pk[0] = f2bf(a[0][j]); pk[1] = f2bf(a[1][j]);
            pk[2] = f2bf(a[2][j]); pk[3] = f2bf(a[3][j]);
            *(s16x4*)&Xt[n8 + j][d0] = pk;
        }
    }
    __syncthreads();

    float* ob = out + (size_t)b * (C_ * (size_t)N_);
    #pragma unroll
    for (int nt = 0; nt < 4; ++nt) {
        const int ntile = w * 4 + nt;
        bf16x8 xfrag0 = *(const bf16x8*)&Xt[ntile * 16 + row][kg * 8];
        bf16x8 xfrag1 = *(const bf16x8*)&Xt[ntile * 16 + row][32 + kg * 8];
        #pragma unroll
        for (int g = 0; g < 4; ++g) {
            f32x4 acc = {};
            acc = __builtin_amdgcn_mfma_f32_16x16x32_bf16(xfrag0, mfrag[0][g], acc, 0, 0, 0);
            acc = __builtin_amdgcn_mfma_f32_16x16x32_bf16(xfrag1, mfrag[1][g], acc, 0, 0, 0);
            __builtin_nontemporal_store(acc,
                (f32x4*)&ob[(size_t)(16 * g + row) * N_ + n0 + ntile * 16 + 4 * kg]);
        }
    }
}

extern "C" void kernel_launch(void* const* d_in, const int* in_sizes, int n_in,
                              void* d_out, int out_size, void* d_ws, size_t ws_size,
                              hipStream_t stream) {
    const float* x = (const float*)d_in[0];   // [16,64,128,128] fp32
    const float* w = (const float*)d_in[1];   // [64,64] fp32
    float* out = (float*)d_out;               // [16,64,128,128] fp32

    unsigned short* gpart = (unsigned short*)d_ws;                    // 4 MiB (bf16)
    unsigned short* Mbf = gpart + (size_t)B_ * KCH * 4096;            // 128 KiB

    gram_kernel<<<dim3(KCH, B_), 256, 0, stream>>>(x, gpart);
    rm_kernel<<<dim3(4, B_), 256, 0, stream>>>(w, gpart, Mbf);
    out_kernel<<<dim3(N_ / 256, B_), 256, 0, stream>>>(x, Mbf, out);
}